// Round 2
// 190.858 us; speedup vs baseline: 1.0026x; 1.0026x over previous
//
#include <hip/hip_runtime.h>
#include <math.h>

#define LN_EPS 1e-5f

// N=512, L=256, P=64
// ws layout (floats):
//   proj (lg lv rg rv) @ 0       262144   [reused by kD2/kC as rm = rs*mu]
//   left  @ 262144   65536
//   right @ 327680   65536
//   Aw    @ 393216   32768
//   Bw    @ 425984   32768
//   rs    @ 458752   262144     [was Cw; now holds rsqrt(var+eps) per (i,j)]
//   (unused) @ 720896 2048
//   cs    @ 722944   128
//   act   @ 723072   513 ints   (act[0]=count, act[1..] = active indices)

typedef __bf16 bf16x8 __attribute__((ext_vector_type(8)));
typedef float f32x16 __attribute__((ext_vector_type(16)));

__device__ __forceinline__ float gelu_f(float x) {
    float x2 = x * x;
    float e = __builtin_amdgcn_exp2f(x * fmaf(0.10294423f, x2, 2.3022079f));
    float r = __builtin_amdgcn_rcpf(e + 1.0f);
    return fmaf(-x, r, x);
}

// ---------- kA: LN(local) @ W_*  +  (bx==64): compaction / zero left+right ----------
__global__ __launch_bounds__(256) void kA(
    const float* __restrict__ loc,
    const float* __restrict__ Wlg, const float* __restrict__ Wlv,
    const float* __restrict__ Wrg, const float* __restrict__ Wrv,
    float* __restrict__ proj, const int* __restrict__ mask,
    int* __restrict__ act, float* __restrict__ left, float* __restrict__ right) {
    const int t = threadIdx.x;
    if (blockIdx.x == 64) {
        if (blockIdx.y == 1) {          // zero left
            float4 z = {0.f, 0.f, 0.f, 0.f};
            for (int idx = t; idx < 16384; idx += 256) ((float4*)left)[idx] = z;
        } else if (blockIdx.y == 2) {   // zero right
            float4 z = {0.f, 0.f, 0.f, 0.f};
            for (int idx = t; idx < 16384; idx += 256) ((float4*)right)[idx] = z;
        } else if (blockIdx.y == 0) {   // compact active indices
            __shared__ int cnt_sh[8];
            const int lane = t & 63, wv = t >> 6;
            int msave[2];
            unsigned long long bsave[2];
#pragma unroll
            for (int ch = 0; ch < 2; ++ch) {
                int m = (mask[ch * 256 + t] != 0);
                unsigned long long b = __ballot(m);
                if (lane == 0) cnt_sh[ch * 4 + wv] = __popcll(b);
                msave[ch] = m;
                bsave[ch] = b;
            }
            __syncthreads();
#pragma unroll
            for (int ch = 0; ch < 2; ++ch) {
                int base = 0;
                for (int u = 0; u < ch * 4 + wv; ++u) base += cnt_sh[u];
                int pos = base + __popcll(bsave[ch] & ((1ull << lane) - 1ull));
                if (msave[ch]) act[1 + pos] = ch * 256 + t;
            }
            if (t == 0) {
                int ctot = 0;
                for (int u = 0; u < 8; ++u) ctot += cnt_sh[u];
                act[0] = ctot;
            }
        }
        return;
    }
    __shared__ float ln_sh[8][260];
    __shared__ float red_sh[128][9];
    const int i0 = blockIdx.x * 8;
    const int mat = blockIdx.y;
    const float* __restrict__ W = (mat == 0) ? Wlg : (mat == 1) ? Wlv
                                 : (mat == 2) ? Wrg : Wrv;
    {
        int row = t >> 5, l32 = t & 31;
        const float4* src = (const float4*)(loc + (i0 + row) * 256);
        float4 v0 = src[l32 * 2];
        float4 v1 = src[l32 * 2 + 1];
        float s = (v0.x + v0.y) + (v0.z + v0.w) + (v1.x + v1.y) + (v1.z + v1.w);
        float ss = v0.x * v0.x + v0.y * v0.y + v0.z * v0.z + v0.w * v0.w +
                   v1.x * v1.x + v1.y * v1.y + v1.z * v1.z + v1.w * v1.w;
#pragma unroll
        for (int off = 1; off < 32; off <<= 1) {
            s += __shfl_xor(s, off);
            ss += __shfl_xor(ss, off);
        }
        float mu = s * (1.f / 256.f);
        float rs = rsqrtf(ss * (1.f / 256.f) - mu * mu + LN_EPS);
        float4 o0, o1;
        o0.x = (v0.x - mu) * rs; o0.y = (v0.y - mu) * rs;
        o0.z = (v0.z - mu) * rs; o0.w = (v0.w - mu) * rs;
        o1.x = (v1.x - mu) * rs; o1.y = (v1.y - mu) * rs;
        o1.z = (v1.z - mu) * rs; o1.w = (v1.w - mu) * rs;
        *(float4*)&ln_sh[row][l32 * 8] = o0;
        *(float4*)&ln_sh[row][l32 * 8 + 4] = o1;
    }
    __syncthreads();

    const int n = t & 127;
    const int kh = t >> 7;
    float acc[8] = {0.f, 0.f, 0.f, 0.f, 0.f, 0.f, 0.f, 0.f};
#pragma unroll 2
    for (int c = 0; c < 32; ++c) {
        const int kc = kh * 128 + c * 4;
        float w0 = W[(kc + 0) * 128 + n];
        float w1 = W[(kc + 1) * 128 + n];
        float w2 = W[(kc + 2) * 128 + n];
        float w3 = W[(kc + 3) * 128 + n];
#pragma unroll
        for (int r = 0; r < 8; ++r) {
            float4 l4 = *(const float4*)&ln_sh[r][kc];
            acc[r] += l4.x * w0 + l4.y * w1 + l4.z * w2 + l4.w * w3;
        }
    }
    if (kh == 1) {
#pragma unroll
        for (int r = 0; r < 8; ++r) red_sh[n][r] = acc[r];
    }
    __syncthreads();
    if (kh == 0) {
#pragma unroll
        for (int r = 0; r < 8; ++r)
            proj[mat * 65536 + (i0 + r) * 128 + n] = acc[r] + red_sh[n][r];
    }
}

// ---------- kB: compacted i,j; dual-accumulator MFMA; dbuf staging; reg-resident lv/rg ----------
// KB_TI=4: with cnt~256, 8x64=512 active blocks -> 2 blocks/CU, 8 waves/CU
// (was KB_TI=8: 256 active blocks = 4 waves/CU, latency-exposed)
#define KB_TI 4
__global__ __launch_bounds__(256) void kB(
    const float* __restrict__ pair, const int* __restrict__ act,
    const float* __restrict__ Wg, const float* __restrict__ Wv,
    const float* __restrict__ lg, const float* __restrict__ lv,
    const float* __restrict__ rg, const float* __restrict__ rv,
    float* __restrict__ left, float* __restrict__ right) {
    __shared__ __bf16 A_sh[2][32][72];
    __shared__ int ji_sh[32];
    __shared__ int ii_sh[KB_TI];

    const int cnt = act[0];
    const int j0 = blockIdx.x * 32;
    const int ibase = blockIdx.y * KB_TI;
    if (j0 >= cnt || ibase >= cnt) return;
    const int nact = min(KB_TI, cnt - ibase);

    const int t = threadIdx.x;
    const int lane = t & 63;
    const int w = t >> 6;
    const int c = lane & 31;
    const int half = lane >> 5;
    const int n = w * 32 + c;

    if (t < 32) ji_sh[t] = act[1 + min(j0 + t, cnt - 1)];
    if (t >= 64 && t < 64 + KB_TI) ii_sh[t - 64] = act[1 + min(ibase + (t - 64), cnt - 1)];
    __syncthreads();

    bf16x8 bg[4], bv[4];
#pragma unroll
    for (int kt = 0; kt < 4; ++kt) {
        bf16x8 vg, vv;
#pragma unroll
        for (int e = 0; e < 8; ++e) {
            int kr = kt * 16 + half * 8 + e;
            vg[e] = (__bf16)Wg[kr * 128 + n];
            vv[e] = (__bf16)Wv[kr * 128 + n];
        }
        bg[kt] = vg; bv[kt] = vv;
    }

    float lvr[16], rgr[16];
    unsigned jmask = 0;
#pragma unroll
    for (int r = 0; r < 16; ++r) {
        int m = 4 * half + (r & 3) + 8 * (r >> 2);
        int j = ji_sh[m];
        lvr[r] = lv[j * 128 + n];
        rgr[r] = rg[j * 128 + n];
        if (j0 + m < cnt) jmask |= (1u << r);
    }

    const int srow = t >> 3;
    const int kseg = (t & 7) * 8;
    float4 p0, p1;
    float plg, prv;
    {
        int iF = ii_sh[0];
        const float* src = pair + ((size_t)iF * 512 + ji_sh[srow]) * 64 + kseg;
        p0 = *(const float4*)src;
        p1 = *(const float4*)(src + 4);
        plg = lg[iF * 128 + n];
        prv = rv[iF * 128 + n];
    }

    auto lnwrite = [&](int buf) {
        float s = (p0.x + p0.y) + (p0.z + p0.w) + (p1.x + p1.y) + (p1.z + p1.w);
        float ss = p0.x * p0.x + p0.y * p0.y + p0.z * p0.z + p0.w * p0.w +
                   p1.x * p1.x + p1.y * p1.y + p1.z * p1.z + p1.w * p1.w;
        s += __shfl_xor(s, 1); ss += __shfl_xor(ss, 1);
        s += __shfl_xor(s, 2); ss += __shfl_xor(ss, 2);
        s += __shfl_xor(s, 4); ss += __shfl_xor(ss, 4);
        float mu = s * (1.f / 64.f);
        float rs = rsqrtf(ss * (1.f / 64.f) - mu * mu + LN_EPS);
        bf16x8 o;
        o[0] = (__bf16)((p0.x - mu) * rs); o[1] = (__bf16)((p0.y - mu) * rs);
        o[2] = (__bf16)((p0.z - mu) * rs); o[3] = (__bf16)((p0.w - mu) * rs);
        o[4] = (__bf16)((p1.x - mu) * rs); o[5] = (__bf16)((p1.y - mu) * rs);
        o[6] = (__bf16)((p1.z - mu) * rs); o[7] = (__bf16)((p1.w - mu) * rs);
        *(bf16x8*)&A_sh[buf][srow][kseg] = o;
    };
    lnwrite(0);
    __syncthreads();

    float racc[16];
#pragma unroll
    for (int r = 0; r < 16; ++r) racc[r] = 0.f;

    for (int ii = 0; ii < nact; ++ii) {
        const int i = ii_sh[ii];
        const float lgi = plg;
        const float rvi = prv;
        if (ii + 1 < nact) {
            int iF = ii_sh[ii + 1];
            const float* src = pair + ((size_t)iF * 512 + ji_sh[srow]) * 64 + kseg;
            p0 = *(const float4*)src;
            p1 = *(const float4*)(src + 4);
            plg = lg[iF * 128 + n];
            prv = rv[iF * 128 + n];
        }

        f32x16 ag = {}; f32x16 av = {};
#pragma unroll
        for (int kt = 0; kt < 4; ++kt) {
            bf16x8 af = *(const bf16x8*)&A_sh[ii & 1][c][kt * 16 + half * 8];
            ag = __builtin_amdgcn_mfma_f32_32x32x16_bf16(af, bg[kt], ag, 0, 0, 0);
            av = __builtin_amdgcn_mfma_f32_32x32x16_bf16(af, bv[kt], av, 0, 0, 0);
        }

        float lsum = 0.f;
#pragma unroll
        for (int r = 0; r < 16; ++r) {
            float pg = ag[r], pv = av[r];
            float lres = gelu_f(lgi + pg) * (lvr[r] + pv);
            float rres = gelu_f(rgr[r] + pg) * (rvi + pv);
            lsum += ((jmask >> r) & 1) ? lres : 0.f;
            racc[r] += rres;
        }
        float tot = lsum + __shfl_xor(lsum, 32);
        if (lane < 32) atomicAdd(&left[i * 128 + n], tot);

        if (ii + 1 < nact) lnwrite((ii + 1) & 1);
        __syncthreads();
    }

#pragma unroll
    for (int r = 0; r < 16; ++r) {
        if ((jmask >> r) & 1) {
            int m = 4 * half + (r & 3) + 8 * (r >> 2);
            atomicAdd(&right[ji_sh[m] * 128 + n], racc[r]);
        }
    }
}

// ---------- kD: kD1 (A/B proj + colsums) and kD2 (C = L@R^T, fused LN-stat precompute) ----------
// kD2 computes per-(i,j) rs = rsqrt(var_s+eps) and rm = rs*mu_s directly
// (row sums of left/right fall out of the existing streaming loop for free),
// removing 16 rsqrtf + 32 broadcast loads per body from kC's critical path.
__global__ __launch_bounds__(256) void kD(
    const float* __restrict__ left, const float* __restrict__ right,
    const float* __restrict__ W_out,
    float* __restrict__ Aw, float* __restrict__ Bw,
    float* __restrict__ rsArr, float* __restrict__ rmArr,
    float* __restrict__ cs) {
    const int bx = blockIdx.x;
    const int t = threadIdx.x;
    if (bx < 256) {   // --- kD2 tile ---
        __shared__ float l_sh[32][68];
        __shared__ float r_sh[32][68];
        const int tx = t & 15, ty = t >> 4;
        const int i0 = (bx & 15) * 32, j0 = (bx >> 4) * 32;
        float acc00 = 0.f, acc01 = 0.f, acc10 = 0.f, acc11 = 0.f;
        float sL0 = 0.f, ssL0 = 0.f, sL1 = 0.f, ssL1 = 0.f;
        float sR0 = 0.f, ssR0 = 0.f, sR1 = 0.f, ssR1 = 0.f;
        for (int kc = 0; kc < 128; kc += 64) {
            __syncthreads();
#pragma unroll
            for (int u = 0; u < 2; ++u) {
                int fi = t + u * 256;
                int row = fi >> 4, kq = (fi & 15) * 4;
                float4 lv4 = *(const float4*)(left + (i0 + row) * 128 + kc + kq);
                float4 rv4 = *(const float4*)(right + (j0 + row) * 128 + kc + kq);
                *(float4*)&l_sh[row][kq] = lv4;
                *(float4*)&r_sh[row][kq] = rv4;
            }
            __syncthreads();
#pragma unroll 8
            for (int k = 0; k < 64; ++k) {
                float l0 = l_sh[ty * 2 + 0][k], l1 = l_sh[ty * 2 + 1][k];
                float r0 = r_sh[tx * 2 + 0][k], r1 = r_sh[tx * 2 + 1][k];
                acc00 += l0 * r0; acc01 += l0 * r1;
                acc10 += l1 * r0; acc11 += l1 * r1;
                sL0 += l0; ssL0 += l0 * l0;
                sL1 += l1; ssL1 += l1 * l1;
                sR0 += r0; ssR0 += r0 * r0;
                sR1 += r1; ssR1 += r1 * r1;
            }
        }
        // per output (i,j): mu_s, var_s, rs; store {rs, rs*mu}
        {
            float sLa[2] = {sL0, sL1}, ssLa[2] = {ssL0, ssL1};
            float sRb[2] = {sR0, sR1}, ssRb[2] = {ssR0, ssR1};
            float accv[2][2] = {{acc00, acc01}, {acc10, acc11}};
#pragma unroll
            for (int a = 0; a < 2; ++a) {
#pragma unroll
                for (int b = 0; b < 2; ++b) {
                    float mu = (sLa[a] + sRb[b]) * (1.f / 128.f);
                    float var = fmaf(-mu, mu,
                                     (ssLa[a] + 2.f * accv[a][b] + ssRb[b]) * (1.f / 128.f));
                    float rs = rsqrtf(var + LN_EPS);
                    size_t idx = (size_t)(i0 + ty * 2 + a) * 512 + (j0 + tx * 2 + b);
                    rsArr[idx] = rs;
                    rmArr[idx] = rs * mu;
                }
            }
        }
    } else {          // --- kD1: two (r, which) jobs per block ---
        const int id = bx - 256;            // 0..511
        const int which = id >> 8;
        const int sub = t >> 7;
        const int tt = t & 127;
        const int r = (id & 255) * 2 + sub;
        const float* src = which ? right : left;
        __shared__ float row_sh[2][128];
        row_sh[sub][tt] = src[r * 128 + tt];
        __syncthreads();
        if (tt < 64) {
            float a = 0.f;
            const float* W2 = W_out + 64 * 64;
#pragma unroll 8
            for (int m = 0; m < 128; ++m) a += row_sh[sub][m] * W2[m * 64 + tt];
            (which ? Bw : Aw)[r * 64 + tt] = a;
        }
        if (id == 0 && t < 64) {
            float c0 = 0.f, c1 = 0.f;
            for (int k = 0; k < 64; ++k) c0 += W_out[k * 64 + t];
            for (int m = 0; m < 128; ++m) c1 += W_out[(64 + m) * 64 + t];
            cs[t] = c0;
            cs[64 + t] = c1;
        }
    }
}

// ---------- kC: 4-deep i-pipelined, barrier-free fragment-direct MFMA ----------
// grid (128, 8); block owns i0..i0+3 x 64 j. 4 independent waves: mt=w&1 (32 j),
// nt=w>>1 (32 n). Pair fragments register-double-buffered. Epilogue reads
// precomputed {rs, rs*mu} per (i,j) — no rsqrt / sums on the critical path.
__global__ __launch_bounds__(256) void kC(
    const float* __restrict__ pair, const float* __restrict__ Wout,
    const float* __restrict__ Aw, const float* __restrict__ Bw,
    const float* __restrict__ rsArr, const float* __restrict__ rmArr,
    const float* __restrict__ cs, float* __restrict__ out) {
    const int t = threadIdx.x;
    const int lane = t & 63;
    const int w = t >> 6;
    const int c = lane & 31;
    const int half = lane >> 5;
    const int i0 = blockIdx.x * 4;
    const int j0 = blockIdx.y * 64;
    const int mt = w & 1;
    const int nt = w >> 1;
    const int n = nt * 32 + c;
    const int jrow = j0 + mt * 32 + c;

    const float* __restrict__ abase = pair + ((size_t)i0 * 512 + jrow) * 64 + half * 8;

    float4 va[8], vb[8];
#pragma unroll
    for (int kt = 0; kt < 4; ++kt) {             // issue i0's pair loads first
        va[2 * kt] = *(const float4*)(abase + kt * 16);
        va[2 * kt + 1] = *(const float4*)(abase + kt * 16 + 4);
    }

    bf16x8 bo[4];                                 // i-invariant: Wout fragments
#pragma unroll
    for (int kt = 0; kt < 4; ++kt) {
        bf16x8 bb;
#pragma unroll
        for (int e = 0; e < 8; ++e)
            bb[e] = (__bf16)Wout[(kt * 16 + half * 8 + e) * 64 + n];
        bo[kt] = bb;
    }
    float Bv[16];                                 // i-invariant: Bw values
#pragma unroll
    for (int r = 0; r < 16; ++r) {
        int jp = j0 + mt * 32 + 4 * half + (r & 3) + 8 * (r >> 2);
        Bv[r] = Bw[jp * 64 + n];
    }
    const float cs1n = cs[64 + n];

    auto body = [&](float4 (&cur)[8], float4 (&nxt)[8], int ii) {
        if (ii < 3) {                             // prefetch next i
            const float* src = abase + (size_t)(ii + 1) * 512 * 64;
#pragma unroll
            for (int kt = 0; kt < 4; ++kt) {
                nxt[2 * kt] = *(const float4*)(src + kt * 16);
                nxt[2 * kt + 1] = *(const float4*)(src + kt * 16 + 4);
            }
        }
        const int i = i0 + ii;
        const float A_in = Aw[i * 64 + n];

        float s = 0.f, ss = 0.f;
#pragma unroll
        for (int u = 0; u < 8; ++u) {
            s += (cur[u].x + cur[u].y) + (cur[u].z + cur[u].w);
            ss += cur[u].x * cur[u].x + cur[u].y * cur[u].y +
                  cur[u].z * cur[u].z + cur[u].w * cur[u].w;
        }
        s += __shfl_xor(s, 32);
        ss += __shfl_xor(ss, 32);
        float mu = s * (1.f / 64.f);
        float rs = rsqrtf(ss * (1.f / 64.f) - mu * mu + LN_EPS);

        f32x16 acc = {};
#pragma unroll
        for (int kt = 0; kt < 4; ++kt) {
            bf16x8 af;
#pragma unroll
            for (int u = 0; u < 2; ++u) {
                float4 vv = cur[2 * kt + u];
                af[u * 4 + 0] = (__bf16)((vv.x - mu) * rs);
                af[u * 4 + 1] = (__bf16)((vv.y - mu) * rs);
                af[u * 4 + 2] = (__bf16)((vv.z - mu) * rs);
                af[u * 4 + 3] = (__bf16)((vv.w - mu) * rs);
            }
            acc = __builtin_amdgcn_mfma_f32_32x32x16_bf16(af, bo[kt], acc, 0, 0, 0);
        }

#pragma unroll
        for (int r = 0; r < 16; ++r) {
            int jp = j0 + mt * 32 + 4 * half + (r & 3) + 8 * (r >> 2);
            size_t idx = (size_t)i * 512 + jp;
            float rsv = rsArr[idx];
            float rmv = rmArr[idx];
            out[idx * 64 + n] =
                fmaf(rsv, A_in + Bv[r], fmaf(-rmv, cs1n, acc[r]));
        }
    };
    body(va, vb, 0);
    body(vb, va, 1);
    body(va, vb, 2);
    body(vb, va, 3);
}

extern "C" void kernel_launch(void* const* d_in, const int* in_sizes, int n_in,
                              void* d_out, int out_size, void* d_ws, size_t ws_size,
                              hipStream_t stream) {
    const float* loc  = (const float*)d_in[0];
    const float* pair = (const float*)d_in[1];
    const int*   mask = (const int*)d_in[2];
    const float* Wpg  = (const float*)d_in[3];
    const float* Wpv  = (const float*)d_in[4];
    const float* Wlg  = (const float*)d_in[5];
    const float* Wlv  = (const float*)d_in[6];
    const float* Wrg  = (const float*)d_in[7];
    const float* Wrv  = (const float*)d_in[8];
    const float* Wout = (const float*)d_in[9];
    float* out = (float*)d_out;
    float* ws = (float*)d_ws;

    float* proj  = ws;            // lg lv rg rv  (dead after kB -> reused as rm)
    float* left  = ws + 262144;
    float* right = ws + 327680;
    float* Aw    = ws + 393216;
    float* Bw    = ws + 425984;
    float* rsA   = ws + 458752;   // rs = rsqrt(var_s + eps) per (i,j)
    float* rmA   = ws;            // rm = rs * mu_s per (i,j), aliases proj
    float* cs    = ws + 722944;
    int*   act   = (int*)(ws + 723072);

    kA<<<dim3(65, 4), 256, 0, stream>>>(loc, Wlg, Wlv, Wrg, Wrv, proj,
                                        mask, act, left, right);
    kB<<<dim3(16, 128), 256, 0, stream>>>(pair, act, Wpg, Wpv,
                                          proj, proj + 65536, proj + 131072,
                                          proj + 196608, left, right);
    kD<<<768, 256, 0, stream>>>(left, right, Wout, Aw, Bw, rsA, rmA, cs);
    kC<<<dim3(128, 8), 256, 0, stream>>>(pair, Wout, Aw, Bw, rsA, rmA, cs, out);
}